// Round 1
// baseline (37.492 us; speedup 1.0000x reference)
//
#include <hip/hip_runtime.h>

// 3x3 median filter, REFLECT padding, NHWC (8,512,512,8) f32.
// One thread = one float4 (4 of the 8 channels of one pixel).
// Median-of-9 via Devillard's 19-compare-exchange network (exact).

#define S2(a, b)                                                            \
  {                                                                         \
    float4 _t;                                                              \
    _t.x = fminf(a.x, b.x); _t.y = fminf(a.y, b.y);                         \
    _t.z = fminf(a.z, b.z); _t.w = fminf(a.w, b.w);                         \
    b.x = fmaxf(a.x, b.x);  b.y = fmaxf(a.y, b.y);                          \
    b.z = fmaxf(a.z, b.z);  b.w = fmaxf(a.w, b.w);                          \
    a = _t;                                                                 \
  }

__global__ __launch_bounds__(256) void MedianFilter2D_kernel(
    const float* __restrict__ x, float* __restrict__ y) {
  constexpr int H = 512, W = 512, C4 = 2;  // C=8 floats -> 2 float4 per pixel

  const int idx = blockIdx.x * 256 + threadIdx.x;  // float4 index
  const int c4 = idx & 1;
  const int w  = (idx >> 1) & (W - 1);
  const int h  = (idx >> 10) & (H - 1);
  const int b  = idx >> 19;

  // reflect (mirror, edge not repeated): -1 -> 1, N -> N-2
  const int hm = (h == 0) ? 1 : h - 1;
  const int hp = (h == H - 1) ? H - 2 : h + 1;
  const int wm = (w == 0) ? 1 : w - 1;
  const int wp = (w == W - 1) ? W - 2 : w + 1;

  const float4* __restrict__ xv = reinterpret_cast<const float4*>(x);
  float4* __restrict__ yv = reinterpret_cast<float4*>(y);

  const int base = b * (H * W * C4);
  const int rm = base + hm * (W * C4);
  const int r0 = base + h  * (W * C4);
  const int rp = base + hp * (W * C4);

  float4 p0 = xv[rm + wm * C4 + c4];
  float4 p1 = xv[rm + w  * C4 + c4];
  float4 p2 = xv[rm + wp * C4 + c4];
  float4 p3 = xv[r0 + wm * C4 + c4];
  float4 p4 = xv[r0 + w  * C4 + c4];
  float4 p5 = xv[r0 + wp * C4 + c4];
  float4 p6 = xv[rp + wm * C4 + c4];
  float4 p7 = xv[rp + w  * C4 + c4];
  float4 p8 = xv[rp + wp * C4 + c4];

  // Devillard opt_med9: 19 compare-exchanges, median lands in p4.
  S2(p1, p2); S2(p4, p5); S2(p7, p8);
  S2(p0, p1); S2(p3, p4); S2(p6, p7);
  S2(p1, p2); S2(p4, p5); S2(p7, p8);
  S2(p0, p3); S2(p5, p8); S2(p4, p7);
  S2(p3, p6); S2(p1, p4); S2(p2, p5);
  S2(p4, p7); S2(p4, p2); S2(p6, p4);
  S2(p4, p2);

  yv[idx] = p4;
}

extern "C" void kernel_launch(void* const* d_in, const int* in_sizes, int n_in,
                              void* d_out, int out_size, void* d_ws, size_t ws_size,
                              hipStream_t stream) {
  const float* x = (const float*)d_in[0];
  float* y = (float*)d_out;
  // total float4 elements: 8*512*512*8/4 = 4,194,304 -> 16384 blocks of 256
  const int total4 = (8 * 512 * 512 * 8) / 4;
  MedianFilter2D_kernel<<<total4 / 256, 256, 0, stream>>>(x, y);
}

// Round 2
// 29.918 us; speedup vs baseline: 1.2532x; 1.2532x over previous
//
#include <hip/hip_runtime.h>

// 3x3 median filter, REFLECT padding, NHWC (8,512,512,8) f32.
// Separable identity: with each horizontal row-triple reduced to
// (lo,mid,hi) = (min3,med3,max3), median9 = med3(max3(lo_r..), med3(mid_r..), min3(hi_r..)).
// Each thread computes a vertical strip of 4 outputs for one float4 (4 channels),
// sharing the 6 row-triple reductions across the 4 sliding windows.

__device__ __forceinline__ float4 f4min3(float4 a, float4 b, float4 c) {
  float4 r;
  r.x = fminf(fminf(a.x, b.x), c.x);
  r.y = fminf(fminf(a.y, b.y), c.y);
  r.z = fminf(fminf(a.z, b.z), c.z);
  r.w = fminf(fminf(a.w, b.w), c.w);
  return r;
}
__device__ __forceinline__ float4 f4max3(float4 a, float4 b, float4 c) {
  float4 r;
  r.x = fmaxf(fmaxf(a.x, b.x), c.x);
  r.y = fmaxf(fmaxf(a.y, b.y), c.y);
  r.z = fmaxf(fmaxf(a.z, b.z), c.z);
  r.w = fmaxf(fmaxf(a.w, b.w), c.w);
  return r;
}
__device__ __forceinline__ float4 f4med3(float4 a, float4 b, float4 c) {
  float4 r;
  r.x = __builtin_amdgcn_fmed3f(a.x, b.x, c.x);
  r.y = __builtin_amdgcn_fmed3f(a.y, b.y, c.y);
  r.z = __builtin_amdgcn_fmed3f(a.z, b.z, c.z);
  r.w = __builtin_amdgcn_fmed3f(a.w, b.w, c.w);
  return r;
}

__global__ __launch_bounds__(256) void MedianFilter2D_kernel(
    const float* __restrict__ x, float* __restrict__ y) {
  constexpr int H = 512, W = 512, C4 = 2;  // C=8 floats -> 2 float4/pixel
  constexpr int RS = 4;                    // output rows per thread

  const int idx = blockIdx.x * 256 + threadIdx.x;
  const int c4 = idx & 1;
  const int w  = (idx >> 1) & (W - 1);
  const int hq = (idx >> 10) & (H / RS - 1);  // wave-uniform
  const int b  = idx >> 17;                   // wave-uniform

  const int h0 = hq * RS;

  // reflect (mirror, edge not repeated)
  const int wm = (w == 0) ? 1 : w - 1;
  const int wp = (w == W - 1) ? W - 2 : w + 1;

  const float4* __restrict__ xv = reinterpret_cast<const float4*>(x);
  float4* __restrict__ yv = reinterpret_cast<float4*>(y);

  const int bbase = b * (H * W * C4);

  float4 lo[RS + 2], mi[RS + 2], hi[RS + 2];
  float4 A[RS + 2], Bv[RS + 2], Cv[RS + 2];

#pragma unroll
  for (int j = 0; j < RS + 2; ++j) {
    int r = h0 - 1 + j;
    r = (r < 0) ? 1 : ((r > H - 1) ? H - 2 : r);  // wave-uniform
    const int rb = bbase + r * (W * C4);
    A[j]  = xv[rb + wm * C4 + c4];
    Bv[j] = xv[rb + w  * C4 + c4];
    Cv[j] = xv[rb + wp * C4 + c4];
  }

#pragma unroll
  for (int j = 0; j < RS + 2; ++j) {
    lo[j] = f4min3(A[j], Bv[j], Cv[j]);
    mi[j] = f4med3(A[j], Bv[j], Cv[j]);
    hi[j] = f4max3(A[j], Bv[j], Cv[j]);
  }

  const int obase = bbase + h0 * (W * C4) + w * C4 + c4;
#pragma unroll
  for (int r = 0; r < RS; ++r) {
    float4 lmax = f4max3(lo[r], lo[r + 1], lo[r + 2]);
    float4 mmed = f4med3(mi[r], mi[r + 1], mi[r + 2]);
    float4 hmin = f4min3(hi[r], hi[r + 1], hi[r + 2]);
    yv[obase + r * (W * C4)] = f4med3(lmax, mmed, hmin);
  }
}

extern "C" void kernel_launch(void* const* d_in, const int* in_sizes, int n_in,
                              void* d_out, int out_size, void* d_ws, size_t ws_size,
                              hipStream_t stream) {
  const float* x = (const float*)d_in[0];
  float* y = (float*)d_out;
  // threads: 8 * (512/4) * 512 * 2 = 1,048,576 -> 4096 blocks of 256
  const int threads_total = 8 * (512 / 4) * 512 * 2;
  MedianFilter2D_kernel<<<threads_total / 256, 256, 0, stream>>>(x, y);
}

// Round 4
// 27.513 us; speedup vs baseline: 1.3627x; 1.0874x over previous
//
#include <hip/hip_runtime.h>

// 3x3 median filter, REFLECT padding, NHWC (8,512,512,8) f32.
// Separable identity: row-triples reduced to (min3,med3,max3);
// median9 = med3(max3(lo_r..), med3(mid_r..), min3(hi_r..)).
// Each thread: vertical strip of 8 outputs for one float4 (4 channels).
// 10 row loads (x3 columns) shared across the 8 sliding windows.

typedef float vf4 __attribute__((ext_vector_type(4)));

__device__ __forceinline__ float4 f4min3(float4 a, float4 b, float4 c) {
  float4 r;
  r.x = fminf(fminf(a.x, b.x), c.x);
  r.y = fminf(fminf(a.y, b.y), c.y);
  r.z = fminf(fminf(a.z, b.z), c.z);
  r.w = fminf(fminf(a.w, b.w), c.w);
  return r;
}
__device__ __forceinline__ float4 f4max3(float4 a, float4 b, float4 c) {
  float4 r;
  r.x = fmaxf(fmaxf(a.x, b.x), c.x);
  r.y = fmaxf(fmaxf(a.y, b.y), c.y);
  r.z = fmaxf(fmaxf(a.z, b.z), c.z);
  r.w = fmaxf(fmaxf(a.w, b.w), c.w);
  return r;
}
__device__ __forceinline__ float4 f4med3(float4 a, float4 b, float4 c) {
  float4 r;
  r.x = __builtin_amdgcn_fmed3f(a.x, b.x, c.x);
  r.y = __builtin_amdgcn_fmed3f(a.y, b.y, c.y);
  r.z = __builtin_amdgcn_fmed3f(a.z, b.z, c.z);
  r.w = __builtin_amdgcn_fmed3f(a.w, b.w, c.w);
  return r;
}

__global__ __launch_bounds__(256) void MedianFilter2D_kernel(
    const float* __restrict__ x, float* __restrict__ y) {
  constexpr int H = 512, W = 512, C4 = 2;  // C=8 floats -> 2 float4/pixel
  constexpr int RS = 8;                    // output rows per thread

  const int idx = blockIdx.x * 256 + threadIdx.x;
  const int c4 = idx & 1;
  const int w  = (idx >> 1) & (W - 1);
  const int hq = (idx >> 10) & (H / RS - 1);  // wave-uniform
  const int b  = idx >> 16;                   // wave-uniform

  const int h0 = hq * RS;

  // reflect (mirror, edge not repeated)
  const int wm = (w == 0) ? 1 : w - 1;
  const int wp = (w == W - 1) ? W - 2 : w + 1;

  const float4* __restrict__ xv = reinterpret_cast<const float4*>(x);
  vf4* __restrict__ yv = reinterpret_cast<vf4*>(y);

  const int bbase = b * (H * W * C4);

  // Sliding lo/mi/hi of the last 3 rows' triple-reductions.
  float4 lo[RS + 2], mi[RS + 2], hi[RS + 2];

#pragma unroll
  for (int j = 0; j < RS + 2; ++j) {
    int r = h0 - 1 + j;
    r = (r < 0) ? 1 : ((r > H - 1) ? H - 2 : r);  // wave-uniform reflect
    const int rb = bbase + r * (W * C4);
    const float4 a = xv[rb + wm * C4 + c4];
    const float4 bb = xv[rb + w * C4 + c4];
    const float4 c = xv[rb + wp * C4 + c4];
    lo[j] = f4min3(a, bb, c);
    mi[j] = f4med3(a, bb, c);
    hi[j] = f4max3(a, bb, c);
  }

  const int obase = bbase + h0 * (W * C4) + w * C4 + c4;
#pragma unroll
  for (int r = 0; r < RS; ++r) {
    const float4 lmax = f4max3(lo[r], lo[r + 1], lo[r + 2]);
    const float4 mmed = f4med3(mi[r], mi[r + 1], mi[r + 2]);
    const float4 hmin = f4min3(hi[r], hi[r + 1], hi[r + 2]);
    const float4 med = f4med3(lmax, mmed, hmin);
    vf4 mv = {med.x, med.y, med.z, med.w};
    __builtin_nontemporal_store(mv, &yv[obase + r * (W * C4)]);
  }
}

extern "C" void kernel_launch(void* const* d_in, const int* in_sizes, int n_in,
                              void* d_out, int out_size, void* d_ws, size_t ws_size,
                              hipStream_t stream) {
  const float* x = (const float*)d_in[0];
  float* y = (float*)d_out;
  // threads: 8 * (512/8) * 512 * 2 = 524,288 -> 2048 blocks of 256
  const int threads_total = 8 * (512 / 8) * 512 * 2;
  MedianFilter2D_kernel<<<threads_total / 256, 256, 0, stream>>>(x, y);
}

// Round 5
// 27.275 us; speedup vs baseline: 1.3746x; 1.0087x over previous
//
#include <hip/hip_runtime.h>

// 3x3 median filter, REFLECT padding, NHWC (8,512,512,8) f32.
// Separable identity: row-triples reduced to (lo,mi,hi) = (min3,med3,max3);
// median9 = med3(max3(lo_r..), med3(mid_r..), min3(hi_r..)).
// Each thread: vertical strip of RS=16 outputs for one float4 (4 channels),
// computed with a rolling 3-row window of reduced triples so only ~3 rows of
// state stay live (low VGPR -> high occupancy), loads/stores fully pipelined.

typedef float vf4 __attribute__((ext_vector_type(4)));

__device__ __forceinline__ float4 f4min3(float4 a, float4 b, float4 c) {
  float4 r;
  r.x = fminf(fminf(a.x, b.x), c.x);
  r.y = fminf(fminf(a.y, b.y), c.y);
  r.z = fminf(fminf(a.z, b.z), c.z);
  r.w = fminf(fminf(a.w, b.w), c.w);
  return r;
}
__device__ __forceinline__ float4 f4max3(float4 a, float4 b, float4 c) {
  float4 r;
  r.x = fmaxf(fmaxf(a.x, b.x), c.x);
  r.y = fmaxf(fmaxf(a.y, b.y), c.y);
  r.z = fmaxf(fmaxf(a.z, b.z), c.z);
  r.w = fmaxf(fmaxf(a.w, b.w), c.w);
  return r;
}
__device__ __forceinline__ float4 f4med3(float4 a, float4 b, float4 c) {
  float4 r;
  r.x = __builtin_amdgcn_fmed3f(a.x, b.x, c.x);
  r.y = __builtin_amdgcn_fmed3f(a.y, b.y, c.y);
  r.z = __builtin_amdgcn_fmed3f(a.z, b.z, c.z);
  r.w = __builtin_amdgcn_fmed3f(a.w, b.w, c.w);
  return r;
}

__global__ __launch_bounds__(256) void MedianFilter2D_kernel(
    const float* __restrict__ x, float* __restrict__ y) {
  constexpr int H = 512, W = 512, C4 = 2;  // C=8 floats -> 2 float4/pixel
  constexpr int RS = 16;                   // output rows per thread

  const int idx = blockIdx.x * 256 + threadIdx.x;
  const int c4 = idx & 1;
  const int w  = (idx >> 1) & (W - 1);
  const int hq = (idx >> 10) & (H / RS - 1);  // wave-uniform
  const int b  = idx >> 15;                   // wave-uniform

  const int h0 = hq * RS;

  // reflect (mirror, edge not repeated)
  const int wm = (w == 0) ? 1 : w - 1;
  const int wp = (w == W - 1) ? W - 2 : w + 1;

  const float4* __restrict__ xv = reinterpret_cast<const float4*>(x);
  vf4* __restrict__ yv = reinterpret_cast<vf4*>(y);

  const int bbase = b * (H * W * C4);
  const int colm = wm * C4 + c4, col0 = w * C4 + c4, colp = wp * C4 + c4;

  // Rolling 3-slot window of row triple-reductions.
  float4 lo[3], mi[3], hi[3];

  // preload rows h0-1 (reflected) and h0 into slots 0,1
  {
    const int rtop = (h0 == 0) ? 1 : h0 - 1;  // wave-uniform reflect
    const int rb = bbase + rtop * (W * C4);
    const float4 a = xv[rb + colm];
    const float4 bb = xv[rb + col0];
    const float4 c = xv[rb + colp];
    lo[0] = f4min3(a, bb, c);
    mi[0] = f4med3(a, bb, c);
    hi[0] = f4max3(a, bb, c);
  }
  {
    const int rb = bbase + h0 * (W * C4);
    const float4 a = xv[rb + colm];
    const float4 bb = xv[rb + col0];
    const float4 c = xv[rb + colp];
    lo[1] = f4min3(a, bb, c);
    mi[1] = f4med3(a, bb, c);
    hi[1] = f4max3(a, bb, c);
  }

  const int obase = bbase + h0 * (W * C4) + col0;
#pragma unroll
  for (int r = 0; r < RS; ++r) {
    // load row h0+r+1 (reflect at bottom), reduce into slot (r+2)%3
    {
      int rr = h0 + r + 1;
      rr = (rr > H - 1) ? H - 2 : rr;  // wave-uniform
      const int rb = bbase + rr * (W * C4);
      const float4 a = xv[rb + colm];
      const float4 bb = xv[rb + col0];
      const float4 c = xv[rb + colp];
      const int s = (r + 2) % 3;
      lo[s] = f4min3(a, bb, c);
      mi[s] = f4med3(a, bb, c);
      hi[s] = f4max3(a, bb, c);
    }
    const int s0 = r % 3, s1 = (r + 1) % 3, s2 = (r + 2) % 3;
    const float4 lmax = f4max3(lo[s0], lo[s1], lo[s2]);
    const float4 mmed = f4med3(mi[s0], mi[s1], mi[s2]);
    const float4 hmin = f4min3(hi[s0], hi[s1], hi[s2]);
    const float4 med = f4med3(lmax, mmed, hmin);
    vf4 mv = {med.x, med.y, med.z, med.w};
    __builtin_nontemporal_store(mv, &yv[obase + r * (W * C4)]);
  }
}

extern "C" void kernel_launch(void* const* d_in, const int* in_sizes, int n_in,
                              void* d_out, int out_size, void* d_ws, size_t ws_size,
                              hipStream_t stream) {
  const float* x = (const float*)d_in[0];
  float* y = (float*)d_out;
  // threads: 8 * (512/16) * 512 * 2 = 262,144 -> 1024 blocks of 256
  const int threads_total = 8 * (512 / 16) * 512 * 2;
  MedianFilter2D_kernel<<<threads_total / 256, 256, 0, stream>>>(x, y);
}